// Round 4
// baseline (47.870 us; speedup 1.0000x reference)
//
#include <hip/hip_runtime.h>

// WaveletDomainLoss: mean |haar_dwt(pred) - haar_dwt(target)|
// DWT is linear => compute haar_dwt(pred - target) on the fly, L1-reduce.
// pred/target: (16, 6, 512, 512) fp32 contiguous. Rows of 512 floats.
// Unit = one float4 column-chunk spanning a row pair => 2 Haar 2x2 blocks.
// N_UNITS = 3145728 = 2048 blocks * 256 threads * 6 units/thread (exact).
//
// R2 lesson: NO acq/rel agent-scope atomics (buffer_wbl2/inv per block wiped
// per-XCD L2 under the streaming wave: 4x regression). Plain atomicAdd(float*)
// is relaxed + device-scope (no cache invalidation) -> safe fusion path.
// out[0] is zeroed by a 4-byte memset node, each block adds its scaled
// partial. Order varies run-to-run (~1e-5 wiggle) -- far below threshold.

#define NBLOCKS 2048
#define NTHREADS 256
#define W 512
#define N_TOTAL 25165824L          // 16*6*512*512
#define ITERS 6
#define STEP_FLOATS 4194304L       // grid-stride step in floats (compile-time)

__global__ __launch_bounds__(NTHREADS) void haar_l1_fused(
    const float* __restrict__ pred,
    const float* __restrict__ tgt,
    float* __restrict__ out)
{
    long tid = (long)blockIdx.x * NTHREADS + threadIdx.x;   // < 524288
    long rp = tid >> 7;            // row-pair index (128 float4 per row)
    long c4 = tid & 127;           // float4 column
    long base0 = rp * (2L * W) + c4 * 4;

    float4 p0[ITERS], p1[ITERS], t0[ITERS], t1[ITERS];

    #pragma unroll
    for (int it = 0; it < ITERS; ++it) {
        long base = base0 + (long)it * STEP_FLOATS;
        p0[it] = *(const float4*)(pred + base);
        p1[it] = *(const float4*)(pred + base + W);
        t0[it] = *(const float4*)(tgt + base);
        t1[it] = *(const float4*)(tgt + base + W);
    }

    float acc = 0.f;
    #pragma unroll
    for (int it = 0; it < ITERS; ++it) {
        float a, b, c, d, s1, s2, d1, d2;
        // block 0: cols {x,y}
        a = p0[it].x - t0[it].x; b = p0[it].y - t0[it].y;
        c = p1[it].x - t1[it].x; d = p1[it].y - t1[it].y;
        s1 = a + b; s2 = c + d; d1 = a - b; d2 = c - d;
        acc += fabsf(s1 + s2) + fabsf(s1 - s2) + fabsf(d1 + d2) + fabsf(d1 - d2);
        // block 1: cols {z,w}
        a = p0[it].z - t0[it].z; b = p0[it].w - t0[it].w;
        c = p1[it].z - t1[it].z; d = p1[it].w - t1[it].w;
        s1 = a + b; s2 = c + d; d1 = a - b; d2 = c - d;
        acc += fabsf(s1 + s2) + fabsf(s1 - s2) + fabsf(d1 + d2) + fabsf(d1 - d2);
    }

    // wave (64-lane) reduction
    #pragma unroll
    for (int off = 32; off > 0; off >>= 1)
        acc += __shfl_down(acc, off, 64);

    __shared__ float wsum[NTHREADS / 64];
    int wave = threadIdx.x >> 6;
    int lane = threadIdx.x & 63;
    if (lane == 0) wsum[wave] = acc;
    __syncthreads();
    if (threadIdx.x == 0) {
        // coeff = 0.5*(±a±b±c±d); we summed without the 0.5. mean over N_TOTAL.
        const float scale = 0.5f / (float)N_TOTAL;
        float part = (wsum[0] + wsum[1] + wsum[2] + wsum[3]) * scale;
        atomicAdd(out, part);   // relaxed, device-scope, no cache invalidation
    }
}

extern "C" void kernel_launch(void* const* d_in, const int* in_sizes, int n_in,
                              void* d_out, int out_size, void* d_ws, size_t ws_size,
                              hipStream_t stream) {
    const float* pred = (const float*)d_in[0];
    const float* tgt  = (const float*)d_in[1];
    float* out = (float*)d_out;

    hipMemsetAsync(out, 0, sizeof(float), stream);
    haar_l1_fused<<<NBLOCKS, NTHREADS, 0, stream>>>(pred, tgt, out);
}

// Round 6
// 35.389 us; speedup vs baseline: 1.3527x; 1.3527x over previous
//
#include <hip/hip_runtime.h>

// WaveletDomainLoss: mean |haar_dwt(pred) - haar_dwt(target)|
// DWT linear => haar_dwt(pred - target) on the fly, L1-reduce.
// pred/target: (16, 6, 512, 512) fp32 contiguous. Rows of 512 floats.
// Unit = one float4 column-chunk spanning a row pair => 2 Haar 2x2 blocks.
// 524288 threads * 6 units/thread = 3145728 units (exact).
//
// Ledger: R2 per-block agent acq/rel fences under streaming  -> 4x regression.
//         R4 2048 single-address device atomicAdds           -> +14us.
//         R5 coop grid.sync (same arrival mechanism as R4, and launch
//            silently failed at 2048 blocks)                 -> dead end.
//         R3 two-kernel, 256thr x 2048blk                    -> 37.1us (best).
// This: same structure, 512thr x 1024blk (half the block epilogues),
// final kernel reads 1024 partials. Main kernel is at ~6.1 TB/s logical,
// ~97% of the 6.29 TB/s measured achievable ceiling.

#define NBLOCKS 1024
#define NTHREADS 512
#define W 512
#define N_TOTAL 25165824L          // 16*6*512*512
#define ITERS 6
#define STEP_FLOATS 4194304L       // grid-stride step in floats (compile-time)

__global__ __launch_bounds__(NTHREADS) void haar_l1_partial(
    const float* __restrict__ pred,
    const float* __restrict__ tgt,
    float* __restrict__ ws)
{
    long tid = (long)blockIdx.x * NTHREADS + threadIdx.x;   // < 524288
    long rp = tid >> 7;            // row-pair index (128 float4 per row)
    long c4 = tid & 127;           // float4 column
    long base0 = rp * (2L * W) + c4 * 4;

    float4 p0[ITERS], p1[ITERS], t0[ITERS], t1[ITERS];

    #pragma unroll
    for (int it = 0; it < ITERS; ++it) {
        long base = base0 + (long)it * STEP_FLOATS;
        p0[it] = *(const float4*)(pred + base);
        p1[it] = *(const float4*)(pred + base + W);
        t0[it] = *(const float4*)(tgt + base);
        t1[it] = *(const float4*)(tgt + base + W);
    }

    float acc = 0.f;
    #pragma unroll
    for (int it = 0; it < ITERS; ++it) {
        float a, b, c, d, s1, s2, d1, d2;
        a = p0[it].x - t0[it].x; b = p0[it].y - t0[it].y;
        c = p1[it].x - t1[it].x; d = p1[it].y - t1[it].y;
        s1 = a + b; s2 = c + d; d1 = a - b; d2 = c - d;
        acc += fabsf(s1 + s2) + fabsf(s1 - s2) + fabsf(d1 + d2) + fabsf(d1 - d2);
        a = p0[it].z - t0[it].z; b = p0[it].w - t0[it].w;
        c = p1[it].z - t1[it].z; d = p1[it].w - t1[it].w;
        s1 = a + b; s2 = c + d; d1 = a - b; d2 = c - d;
        acc += fabsf(s1 + s2) + fabsf(s1 - s2) + fabsf(d1 + d2) + fabsf(d1 - d2);
    }

    // wave (64-lane) reduction
    #pragma unroll
    for (int off = 32; off > 0; off >>= 1)
        acc += __shfl_down(acc, off, 64);

    __shared__ float wsum[NTHREADS / 64];
    int wave = threadIdx.x >> 6;
    int lane = threadIdx.x & 63;
    if (lane == 0) wsum[wave] = acc;
    __syncthreads();
    if (threadIdx.x == 0) {
        float s = 0.f;
        #pragma unroll
        for (int i = 0; i < NTHREADS / 64; ++i) s += wsum[i];
        ws[blockIdx.x] = s;
    }
}

__global__ __launch_bounds__(256) void haar_l1_final(
    const float* __restrict__ ws,
    float* __restrict__ out)
{
    float acc = 0.f;
    #pragma unroll
    for (int i = 0; i < NBLOCKS / 256; ++i)
        acc += ws[i * 256 + threadIdx.x];

    #pragma unroll
    for (int off = 32; off > 0; off >>= 1)
        acc += __shfl_down(acc, off, 64);

    __shared__ float wsum[4];
    int wave = threadIdx.x >> 6;
    int lane = threadIdx.x & 63;
    if (lane == 0) wsum[wave] = acc;
    __syncthreads();
    if (threadIdx.x == 0) {
        // coeff = 0.5*(±a±b±c±d); we summed without the 0.5. mean over N_TOTAL.
        const float scale = 0.5f / (float)N_TOTAL;
        out[0] = (wsum[0] + wsum[1] + wsum[2] + wsum[3]) * scale;
    }
}

extern "C" void kernel_launch(void* const* d_in, const int* in_sizes, int n_in,
                              void* d_out, int out_size, void* d_ws, size_t ws_size,
                              hipStream_t stream) {
    const float* pred = (const float*)d_in[0];
    const float* tgt  = (const float*)d_in[1];
    float* out = (float*)d_out;
    float* ws  = (float*)d_ws;   // NBLOCKS floats = 4 KiB

    haar_l1_partial<<<NBLOCKS, NTHREADS, 0, stream>>>(pred, tgt, ws);
    haar_l1_final<<<1, 256, 0, stream>>>(ws, out);
}